// Round 12
// baseline (50.424 us; speedup 1.0000x reference)
//
#include <hip/hip_runtime.h>
#include <stdint.h>

#define DEV __device__ __forceinline__

constexpr int Bb   = 256;
constexpr int Ss   = 4096;
constexpr int HIDN = 16;
constexpr int VDN  = 6;
constexpr int WINN = 16;

constexpr int BPG   = 16;             // batches per group (mfma16 N dim)
constexpr int NG    = Bb / BPG;       // 16 groups
constexpr int CHUNK = 16;
constexpr int WARM  = 16;
constexpr int NCH   = Ss / CHUNK;     // 256 chunks -> 4096 chains
constexpr int NPH   = (CHUNK + WARM) / 4;   // 8 phases
constexpr int EPH   = WARM / 4;             // emit from phase 4

// wsl: [G][t][48 uint2]: entry q*16+b = (pk(L[4q],L[4q+1]), pk(L[4q+2],L[4q+3]))
//      q<3 only; q=3 slots ([1,0,0,0]) are compile-time constants in rnn.
// wsc: [G][t][b][3 uint2] = 6 (cos,sin) f16 pairs
constexpr size_t WSL_BYTES = (size_t)NG * Ss * 48 * 8;    // 25.2 MB
constexpr size_t WSC_BYTES = (size_t)NG * Ss * BPG * 24;  // 25.2 MB

typedef __fp16 h2v   __attribute__((ext_vector_type(2)));
typedef __fp16 f16x8 __attribute__((ext_vector_type(8)));
typedef float  f32x4 __attribute__((ext_vector_type(4)));

DEV uint32_t pk16(float a, float b) {
    h2v t = __builtin_amdgcn_cvt_pkrtz(a, b);
    uint32_t u; __builtin_memcpy(&u, &t, 4); return u;
}
DEV void up16(uint32_t u, float& a, float& b) {
    h2v t; __builtin_memcpy(&t, &u, 4);
    a = (float)t[0]; b = (float)t[1];
}
DEV f32x4 MF16(const uint32_t* a, const uint32_t* b, f32x4 c) {
    f16x8 av, bv;
    __builtin_memcpy(&av, a, 16);
    __builtin_memcpy(&bv, b, 16);
    return __builtin_amdgcn_mfma_f32_16x16x32_f16(av, bv, c, 0, 0, 0);
}

// legacy helpers for the fallback kernel
template<int C> DEV int   dpp_i(int v)  { return __builtin_amdgcn_update_dpp(0, v, C, 0xF, 0xF, false); }
template<int C> DEV float dpp_f(float v){ return __int_as_float(dpp_i<C>(__float_as_int(v))); }
#define DPP_ALL(X) X(1,0x121) X(2,0x122) X(3,0x123) X(4,0x124) X(5,0x125) X(6,0x126) X(7,0x127) \
  X(8,0x128) X(9,0x129) X(10,0x12A) X(11,0x12B) X(12,0x12C) X(13,0x12D) X(14,0x12E) X(15,0x12F)

// ===================== K1: FIR + mag -> L records + cos/sin =================
__global__ __launch_bounds__(256, 4) void boja_front16(
    const float* __restrict__ x,
    const float* __restrict__ fIw, const float* __restrict__ fQw,
    uint2* __restrict__ wsl, uint2* __restrict__ wsc)
{
    __shared__ __align__(8) uint2 lsl[16 * 48];   // [t][q*16+b]
    __shared__ __align__(8) uint2 lsc[16 * 48];   // [t][b*3+k]

    const int tid = threadIdx.x;
    const int tl  = tid & 15;            // t within block (coalesced x reads)
    const int b_  = tid >> 4;            // 0..15
    const int G   = blockIdx.y;
    const int t0  = blockIdx.x * 16;
    const int t   = t0 + tl;
    const int b   = G * BPG + b_;
    const int id  = b * Ss + t;
    const float2* x2 = (const float2*)x;

    float wI[WINN], wQ[WINN];
    if (t >= WINN - 1) {
#pragma unroll
        for (int w = 0; w < WINN; ++w) { float2 v = x2[id - 15 + w]; wI[w] = v.x; wQ[w] = v.y; }
    } else {
#pragma unroll
        for (int w = 0; w < WINN; ++w) {
            int ts = t - 15 + w;
            float2 v = (ts >= 0) ? x2[id - 15 + w] : make_float2(0.f, 0.f);
            wI[w] = v.x; wQ[w] = v.y;
        }
    }
    float aI[VDN], aQ[VDN];
#pragma unroll
    for (int v = 0; v < VDN; ++v) { aI[v] = 0.f; aQ[v] = 0.f; }
#pragma unroll
    for (int w = 0; w < WINN; ++w) {
#pragma unroll
        for (int v = 0; v < VDN; ++v) {
            aI[v] = fmaf( wI[w], fIw[v*16+w], aI[v]);
            aI[v] = fmaf(-wQ[w], fQw[v*16+w], aI[v]);
            aQ[v] = fmaf( wI[w], fQw[v*16+w], aQ[v]);
            aQ[v] = fmaf( wQ[w], fIw[v*16+w], aQ[v]);
        }
    }
    float mg[VDN], mq[VDN];
    uint32_t sc[VDN];
#pragma unroll
    for (int v = 0; v < VDN; ++v) {
        float m2 = fmaf(aI[v], aI[v], aQ[v]*aQ[v]);
        mg[v] = __builtin_amdgcn_sqrtf(m2) + 1e-8f;
        mq[v] = mg[v] * mg[v];
        float iv = __builtin_amdgcn_rcpf(mg[v]);
        sc[v] = pk16(aI[v]*iv, aQ[v]*iv);   // (cos, sin)
    }
    // L record entries (kmap(q,e)=4q+e): q=0: L0-3; q=1: L4,L5,Q0,Q1; q=2: Q2-5
    lsl[tl*48 +  0 + b_] = make_uint2(pk16(mg[0], mg[1]), pk16(mg[2], mg[3]));
    lsl[tl*48 + 16 + b_] = make_uint2(pk16(mg[4], mg[5]), pk16(mq[0], mq[1]));
    lsl[tl*48 + 32 + b_] = make_uint2(pk16(mq[2], mq[3]), pk16(mq[4], mq[5]));
    lsc[tl*48 + b_*3 + 0] = make_uint2(sc[0], sc[1]);
    lsc[tl*48 + b_*3 + 1] = make_uint2(sc[2], sc[3]);
    lsc[tl*48 + b_*3 + 2] = make_uint2(sc[4], sc[5]);
    __syncthreads();
    // coalesced flush: 768 uint2 each, 3 rounds of 256
#pragma unroll
    for (int r = 0; r < 3; ++r) {
        int idx = r*256 + tid;
        int tq2 = idx / 48, e = idx - tq2*48;
        wsl[(size_t)(G*Ss + t0 + tq2) * 48 + e] = lsl[idx];
        wsc[(size_t)(G*Ss + t0 + tq2) * 48 + e] = lsc[idx];
    }
}

// ===================== K2: 16x16 MFMA recurrence + output ===================
__global__ __launch_bounds__(64, 4) void boja_rnn16(
    const uint2* __restrict__ wsl, const uint2* __restrict__ wsc,
    const float* __restrict__ h0,
    const float* __restrict__ Wfh, const float* __restrict__ Wgh,
    const float* __restrict__ Wfi, const float* __restrict__ bfi,
    const float* __restrict__ Wgi, const float* __restrict__ bgi,
    const float* __restrict__ WoI, const float* __restrict__ boI,
    const float* __restrict__ WoQ, const float* __restrict__ boQ,
    float* __restrict__ out)
{
    const int l  = threadIdx.x;
    const int b_ = l & 15;               // B col = batch ; A row = output j row m_
    const int q  = l >> 4;               // k-group / C row-group
    const int G  = blockIdx.x & (NG - 1);
    const int ci = blockIdx.x >> 4;      // 0..255

    const int t_out0  = ci * CHUNK;
    const int t_start = t_out0 - WARM;
    const bool useh0  = (t_start <= 0);

    const float CF = -1.4426950408889634f;
    const float CG =  2.8853900817779268f;

    // A fragments, kmap(q,e)=4q+e (e<4); e>=4 -> k>=16 zero-pad
    uint32_t a1f[4] = {0,0,0,0}, a1g[4] = {0,0,0,0};
    uint32_t a2f[4] = {0,0,0,0}, a2g[4] = {0,0,0,0};
    const int m_ = b_;
#pragma unroll
    for (int d = 0; d < 2; ++d) {
        const int k0 = 4*q + 2*d, k1 = k0 + 1;
        a1f[d] = pk16(Wfh[m_*16 + k0]*CF, Wfh[m_*16 + k1]*CF);
        a1g[d] = pk16(Wgh[m_*16 + k0]*CG, Wgh[m_*16 + k1]*CG);
        auto uf = [&](int k)->float { return (k < 12) ? Wfi[m_*12 + k] : ((k == 12) ? bfi[m_] : 0.f); };
        auto ug = [&](int k)->float { return (k < 12) ? Wgi[m_*12 + k] : ((k == 12) ? bgi[m_] : 0.f); };
        a2f[d] = pk16(uf(k0)*CF, uf(k1)*CF);
        a2g[d] = pk16(ug(k0)*CG, ug(k1)*CG);
    }

    // output projection for this lane's rows j = 4q+r
    float woi[4], woq[4];
#pragma unroll
    for (int r = 0; r < 4; ++r) { woi[r] = WoI[4*q + r]; woq[r] = WoQ[4*q + r]; }
    const float bo_i = boI[0], bo_q = boQ[0];

    float h0r[4];
    if (useh0) {
        float4 p = *(const float4*)(h0 + (size_t)(G*BPG + b_) * HIDN + 4*q);
        h0r[0]=p.x; h0r[1]=p.y; h0r[2]=p.z; h0r[3]=p.w;
    }
    float hreg[4] = {0.f, 0.f, 0.f, 0.f};
    uint32_t b1[4] = {0u, 0u, 0u, 0u};
    f32x4 zero4; zero4[0]=0.f; zero4[1]=0.f; zero4[2]=0.f; zero4[3]=0.f;

    // L pointer (q<3 real; q=3 lanes use constants)
    const uint2* lp = wsl + (size_t)G * Ss * 48 + (q < 3 ? q : 0) * 16 + b_;
    const uint2* cpb = wsc + (size_t)G * Ss * 48 + b_ * 3;   // + t*48
    // cs offsets per q: q0:(0,1) q1:(2,0) q2:(1,2) q3:(0,1)  [v-pairs for rows]
    const int o0 = (q == 1) ? 2 : ((q == 2) ? 1 : 0);
    const int o1 = (q == 2) ? 2 : ((q == 1) ? 0 : 1);
    float2* outp = (float2*)out + (size_t)(G*BPG + b_) * Ss;

    uint2 LB[3][4];
    uint2 CB[2][4][2];

    auto loadL = [&](uint2 (&B)[4], int tb) {
#pragma unroll
        for (int s = 0; s < 4; ++s) {
            int tq2 = tb + s; tq2 = (tq2 < 0) ? 0 : tq2;
            uint2 v = lp[(size_t)tq2 * 48];
            if (q == 3) v = make_uint2(0x00003C00u, 0u);   // [1,0,0,0]
            B[s] = v;
        }
    };
    auto loadC = [&](uint2 (&C)[4][2], int tb) {
#pragma unroll
        for (int s = 0; s < 4; ++s) {
            const uint2* base = cpb + (size_t)(tb + s) * 48;
            C[s][0] = base[o0];
            C[s][1] = base[o1];
        }
    };

    loadL(LB[0], t_start);
    loadL(LB[1], t_start + 4);

#define PHASE(P) { \
    const int tb = t_start + 4*(P); \
    if ((P) + 2 < NPH) loadL(LB[((P)+2)%3], t_start + 4*((P)+2)); \
    if ((P) + 1 >= EPH && (P) + 1 < NPH) loadC(CB[((P)+1)&1], t_start + 4*((P)+1)); \
    float ob[8]; \
    _Pragma("unroll") \
    for (int s = 0; s < 4; ++s) { \
        if (useh0 && tb + s == 0) { \
            _Pragma("unroll") for (int r = 0; r < 4; ++r) hreg[r] = h0r[r]; \
            b1[0] = pk16(hreg[0], hreg[1]); b1[1] = pk16(hreg[2], hreg[3]); \
        } \
        uint32_t Lfr[4]; Lfr[0] = LB[(P)%3][s].x; Lfr[1] = LB[(P)%3][s].y; Lfr[2] = 0u; Lfr[3] = 0u; \
        f32x4 accf = MF16(a2f, Lfr, zero4); \
        f32x4 accg = MF16(a2g, Lfr, zero4); \
        accf = MF16(a1f, b1, accf); \
        accg = MF16(a1g, b1, accg); \
        _Pragma("unroll") \
        for (int r = 0; r < 4; ++r) { \
            float f = __builtin_amdgcn_rcpf(1.0f + __builtin_amdgcn_exp2f(accf[r])); \
            float g = fmaf(-2.0f, __builtin_amdgcn_rcpf(1.0f + __builtin_amdgcn_exp2f(accg[r])), 1.0f); \
            hreg[r] = fmaf(f, hreg[r] - g, g); \
        } \
        b1[0] = pk16(hreg[0], hreg[1]); b1[1] = pk16(hreg[2], hreg[3]); \
        if ((P) >= EPH) { \
            float c0,s0,c1,s1,c2,s2,c3,s3; \
            up16(CB[(P)&1][s][0].x, c0, s0); up16(CB[(P)&1][s][0].y, c1, s1); \
            up16(CB[(P)&1][s][1].x, c2, s2); up16(CB[(P)&1][s][1].y, c3, s3); \
            float oI = hreg[0]*c0*woi[0] + hreg[1]*c1*woi[1] + hreg[2]*c2*woi[2] + hreg[3]*c3*woi[3]; \
            float oQ = hreg[0]*s0*woq[0] + hreg[1]*s1*woq[1] + hreg[2]*s2*woq[2] + hreg[3]*s3*woq[3]; \
            oI += __shfl_xor(oI, 16, 64); oI += __shfl_xor(oI, 32, 64); \
            oQ += __shfl_xor(oQ, 16, 64); oQ += __shfl_xor(oQ, 32, 64); \
            oI += bo_i; oQ += bo_q; \
            ob[s*2] = oI - oQ; ob[s*2+1] = oI + oQ; \
        } \
    } \
    if ((P) >= EPH && l < 16) { \
        float4* po = (float4*)(outp + tb); \
        po[0] = make_float4(ob[0], ob[1], ob[2], ob[3]); \
        po[1] = make_float4(ob[4], ob[5], ob[6], ob[7]); \
    } \
}

    PHASE(0)  PHASE(1)  PHASE(2)  PHASE(3)
    PHASE(4)  PHASE(5)  PHASE(6)  PHASE(7)
#undef PHASE
}

// ======================= Fallback (known-good v2) ===========================
__global__ __launch_bounds__(64, 2) void bojanet_v2(
    const float* __restrict__ x,   const float* __restrict__ h0,
    const float* __restrict__ fIw, const float* __restrict__ fQw,
    const float* __restrict__ Wfi, const float* __restrict__ bfi,
    const float* __restrict__ Wfh, const float* __restrict__ Wgi,
    const float* __restrict__ bgi, const float* __restrict__ Wgh,
    const float* __restrict__ WoI, const float* __restrict__ boI,
    const float* __restrict__ WoQ, const float* __restrict__ boQ,
    float* __restrict__ out)
{
    constexpr int FCH = 128, FWR = 64, FSB = 16;
    __shared__ __align__(16) float s_fi[FSB * 80];
    __shared__ __align__(16) float s_gi[FSB * 80];
    __shared__ __align__(16) float s_h [FSB * 68];
    __shared__ float s_sc[4 * 12 * 17];

    const int lane = threadIdx.x;
    const int j  = lane & 15;
    const int bl = lane >> 4;
    const int ci = blockIdx.x;
    const int b0 = blockIdx.y * 4;
    const int t_out0  = ci * FCH;
    const int t_start = ci ? (t_out0 - FWR) : 0;
    const int t_end   = t_out0 + FCH;

    int c[16]; c[0] = j;
#define CSET(K,CTL) c[K] = dpp_i<CTL>(j);
    DPP_ALL(CSET)
#undef CSET
    float wf[16], wg[16];
#pragma unroll
    for (int k = 0; k < 16; ++k) { wf[k] = Wfh[j*16 + c[k]]; wg[k] = Wgh[j*16 + c[k]]; }

    float h = (ci == 0) ? h0[(b0 + bl) * HIDN + j] : 0.0f;
    const float2* x2   = (const float2*)x + (size_t)(b0 + bl) * Ss;
    float2*       out2 = (float2*)out     + (size_t)(b0 + bl) * Ss;

    for (int tb = t_start; tb < t_end; tb += FSB) {
        const bool emit = (tb >= t_out0);
        {
            const int tg = tb + j;
            float wI[WINN], wQ[WINN];
            if (tb >= WINN - 1) {
#pragma unroll
                for (int w = 0; w < WINN; ++w) { float2 v = x2[tg - 15 + w]; wI[w] = v.x; wQ[w] = v.y; }
            } else {
#pragma unroll
                for (int w = 0; w < WINN; ++w) {
                    int ts = tg - 15 + w;
                    float2 v = (ts >= 0) ? x2[ts] : make_float2(0.f, 0.f);
                    wI[w] = v.x; wQ[w] = v.y;
                }
            }
            float aI[VDN], aQ[VDN];
#pragma unroll
            for (int v = 0; v < VDN; ++v) { aI[v] = 0.f; aQ[v] = 0.f; }
#pragma unroll
            for (int w = 0; w < WINN; ++w) {
#pragma unroll
                for (int v = 0; v < VDN; ++v) {
                    aI[v] = fmaf( wI[w], fIw[v*16+w], aI[v]);
                    aI[v] = fmaf(-wQ[w], fQw[v*16+w], aI[v]);
                    aQ[v] = fmaf( wI[w], fQw[v*16+w], aQ[v]);
                    aQ[v] = fmaf( wQ[w], fIw[v*16+w], aQ[v]);
                }
            }
            float L[12];
#pragma unroll
            for (int v = 0; v < VDN; ++v) {
                float m2 = fmaf(aI[v], aI[v], aQ[v]*aQ[v]);
                float mg = __builtin_amdgcn_sqrtf(m2) + 1e-8f;
                L[v] = mg; L[6+v] = mg*mg;
                if (emit) {
                    float iv = __builtin_amdgcn_rcpf(mg);
                    s_sc[(bl*12 + v  )*17 + j] = aI[v] * iv;
                    s_sc[(bl*12 + 6+v)*17 + j] = aQ[v] * iv;
                }
            }
            float fi[16], gi[16];
#pragma unroll
            for (int k = 0; k < 16; ++k) { fi[k] = bfi[k]; gi[k] = bgi[k]; }
#pragma unroll
            for (int ll = 0; ll < 12; ++ll) {
#pragma unroll
                for (int k = 0; k < 16; ++k) {
                    fi[k] = fmaf(L[ll], Wfi[k*12+ll], fi[k]);
                    gi[k] = fmaf(L[ll], Wgi[k*12+ll], gi[k]);
                }
            }
            float* pf = &s_fi[j*80 + bl*20];
            float* pg = &s_gi[j*80 + bl*20];
#pragma unroll
            for (int qq = 0; qq < 4; ++qq) {
                *(float4*)(pf + 4*qq) = make_float4(fi[4*qq], fi[4*qq+1], fi[4*qq+2], fi[4*qq+3]);
                *(float4*)(pg + 4*qq) = make_float4(gi[4*qq], gi[4*qq+1], gi[4*qq+2], gi[4*qq+3]);
            }
        }
        __asm__ volatile("s_waitcnt lgkmcnt(0)" ::: "memory");
        {
            const int rb = bl*20 + j;
            float pf0 = s_fi[rb], pf1 = s_fi[80 + rb];
            float pg0 = s_gi[rb], pg1 = s_gi[80 + rb];
#pragma unroll
            for (int tt = 0; tt < FSB; ++tt) {
                const int nx = (tt + 2 < FSB) ? tt + 2 : FSB - 1;
                float pfn = s_fi[nx*80 + rb];
                float pgn = s_gi[nx*80 + rb];
                float hr[16]; hr[0] = h;
#define HSET(K,CTL) hr[K] = dpp_f<CTL>(h);
                DPP_ALL(HSET)
#undef HSET
                float af0 = pf0, af1 = 0.f, ag0 = pg0, ag1 = 0.f;
#pragma unroll
                for (int k = 0; k < 8; ++k) {
                    af0 = fmaf(wf[k],   hr[k],   af0);
                    ag0 = fmaf(wg[k],   hr[k],   ag0);
                    af1 = fmaf(wf[k+8], hr[k+8], af1);
                    ag1 = fmaf(wg[k+8], hr[k+8], ag1);
                }
                float zf = af0 + af1, zg = ag0 + ag1;
                float f = __builtin_amdgcn_rcpf(1.0f + __builtin_amdgcn_exp2f(zf * -1.4426950408889634f));
                float g = fmaf(-2.0f, __builtin_amdgcn_rcpf(1.0f + __builtin_amdgcn_exp2f(zg * 2.8853900817779268f)), 1.0f);
                h = fmaf(f, h - g, g);
                s_h[tt*68 + bl*16 + j] = h;
                pf0 = pf1; pf1 = pfn; pg0 = pg1; pg1 = pgn;
            }
        }
        __asm__ volatile("s_waitcnt lgkmcnt(0)" ::: "memory");
        if (emit) {
            const int tg = tb + j;
            float hv[16];
#pragma unroll
            for (int qq = 0; qq < 4; ++qq) {
                float4 t4 = *(const float4*)&s_h[j*68 + bl*16 + 4*qq];
                hv[4*qq] = t4.x; hv[4*qq+1] = t4.y; hv[4*qq+2] = t4.z; hv[4*qq+3] = t4.w;
            }
            float cs[12];
#pragma unroll
            for (int k = 0; k < 12; ++k) cs[k] = s_sc[(bl*12 + k)*17 + j];
            float oI = boI[0], oQ = boQ[0];
#pragma unroll
            for (int k = 0; k < 16; ++k) {
                int v = (k < 6) ? k : ((k < 12) ? k - 6 : k - 12);
                oI = fmaf(hv[k]*cs[v],   WoI[k], oI);
                oQ = fmaf(hv[k]*cs[6+v], WoQ[k], oQ);
            }
            out2[tg] = make_float2(oI - oQ, oI + oQ);
        }
        __asm__ volatile("s_waitcnt lgkmcnt(0)" ::: "memory");
    }
}

extern "C" void kernel_launch(void* const* d_in, const int* in_sizes, int n_in,
                              void* d_out, int out_size, void* d_ws, size_t ws_size,
                              hipStream_t stream) {
    const float* x   = (const float*)d_in[0];
    const float* h0  = (const float*)d_in[1];
    const float* fIw = (const float*)d_in[2];
    const float* fQw = (const float*)d_in[3];
    const float* Wfi = (const float*)d_in[4];
    const float* bfi = (const float*)d_in[5];
    const float* Wfh = (const float*)d_in[6];
    const float* Wgi = (const float*)d_in[7];
    const float* bgi = (const float*)d_in[8];
    const float* Wgh = (const float*)d_in[9];
    const float* WoI = (const float*)d_in[10];
    const float* boI = (const float*)d_in[11];
    const float* WoQ = (const float*)d_in[12];
    const float* boQ = (const float*)d_in[13];
    float* out = (float*)d_out;

    if (ws_size >= WSL_BYTES + WSC_BYTES) {
        uint2* wsl = (uint2*)d_ws;
        uint2* wsc = (uint2*)((char*)d_ws + WSL_BYTES);
        boja_front16<<<dim3(Ss/16, NG), 256, 0, stream>>>(x, fIw, fQw, wsl, wsc);
        boja_rnn16<<<dim3(NG * NCH), 64, 0, stream>>>(
            wsl, wsc, h0, Wfh, Wgh, Wfi, bfi, Wgi, bgi, WoI, boI, WoQ, boQ, out);
    } else {
        bojanet_v2<<<dim3(32, Bb / 4), 64, 0, stream>>>(
            x, h0, fIw, fQw, Wfi, bfi, Wfh, Wgi, bgi, Wgh, WoI, boI, WoQ, boQ, out);
    }
}